// Round 2
// baseline (578.592 us; speedup 1.0000x reference)
//
#include <hip/hip_runtime.h>

#define M_DIM 8192
#define N_DIM 4096
#define K_DIM 4096

typedef __attribute__((ext_vector_type(8))) __bf16 bf16x8;
typedef __attribute__((ext_vector_type(4))) __bf16 bf16x4;
typedef __attribute__((ext_vector_type(4))) float floatx4;

// ---------- async global->LDS, 16B per lane (wave-uniform LDS base) ----------
__device__ __forceinline__ void async_copy16(const void* g, void* l) {
    __builtin_amdgcn_global_load_lds(
        (const __attribute__((address_space(1))) void*)g,
        (__attribute__((address_space(3))) void*)l,
        16, 0, 0);
}

// ---------- deterministic reductions (fp64) ----------
__device__ __forceinline__ double wave_reduce_d(double v) {
    #pragma unroll
    for (int o = 32; o > 0; o >>= 1) v += __shfl_down(v, o, 64);
    return v;
}
__device__ __forceinline__ unsigned wave_reduce_u(unsigned v) {
    #pragma unroll
    for (int o = 32; o > 0; o >>= 1) v += __shfl_down(v, o, 64);
    return v;
}

// K1 (fused): blocks [0,2048) -> partial sums of |W|; blocks [2048,10240) -> x fp32->bf16
__global__ __launch_bounds__(256) void k_pre(const float4* __restrict__ w4,
                                             double* __restrict__ part,
                                             const float4* __restrict__ x4,
                                             bf16x4* __restrict__ xb) {
    const int tid = threadIdx.x;
    if (blockIdx.x < 2048) {
        int idx = blockIdx.x * 256 + tid;
        double s = 0.0;
        #pragma unroll
        for (int it = 0; it < 8; ++it) {
            float4 v = w4[idx + it * (2048 * 256)];
            s += (double)fabsf(v.x) + (double)fabsf(v.y) +
                 (double)fabsf(v.z) + (double)fabsf(v.w);
        }
        s = wave_reduce_d(s);
        __shared__ double sm[4];
        if ((tid & 63) == 0) sm[tid >> 6] = s;
        __syncthreads();
        if (tid == 0) part[blockIdx.x] = sm[0] + sm[1] + sm[2] + sm[3];
    } else {
        int idx = (blockIdx.x - 2048) * 256 + tid;
        #pragma unroll
        for (int it = 0; it < 4; ++it) {
            int i = idx + it * (8192 * 256);
            float4 v = x4[i];
            bf16x4 o;
            o[0] = (__bf16)v.x; o[1] = (__bf16)v.y;
            o[2] = (__bf16)v.z; o[3] = (__bf16)v.w;
            xb[i] = o;
        }
    }
}

// K2: block-redundant delta from part[2048]; quantize; masked partial sums.
// Per-element math is BIT-IDENTICAL to the round-1 passing kernel (f64 delta/compare).
__global__ __launch_bounds__(256) void k_quant(const float4* __restrict__ w4,
                                               bf16x4* __restrict__ tern,
                                               const double* __restrict__ part,
                                               double* __restrict__ scal,
                                               double* __restrict__ pm,
                                               unsigned* __restrict__ pc) {
    const int tid = threadIdx.x;
    // redundant reduce -> delta (identical order in every block -> identical value)
    double s = 0.0;
    #pragma unroll
    for (int i = 0; i < 8; ++i) s += part[tid + i * 256];
    s = wave_reduce_d(s);
    __shared__ double sm[4];
    if ((tid & 63) == 0) sm[tid >> 6] = s;
    __syncthreads();
    const double mean = (sm[0] + sm[1] + sm[2] + sm[3]) * (1.0 / 16777216.0);
    const double delta = 0.7 * mean;
    if (blockIdx.x == 0 && tid == 0) scal[0] = mean;   // alpha fallback

    int idx = blockIdx.x * 256 + tid;
    double msum = 0.0;
    unsigned cnt = 0;
    #pragma unroll
    for (int it = 0; it < 8; ++it) {
        int i = idx + it * (2048 * 256);
        float4 v = w4[i];
        float e[4] = {v.x, v.y, v.z, v.w};
        bf16x4 o;
        #pragma unroll
        for (int c = 0; c < 4; ++c) {
            float wv = e[c];
            float t = ((double)wv > delta) ? 1.0f
                    : (((double)wv < -delta) ? -1.0f : 0.0f);
            if (t != 0.0f) { msum += (double)fabsf(wv); cnt++; }
            o[c] = (__bf16)t;
        }
        tern[i] = o;
    }
    msum = wave_reduce_d(msum);
    cnt  = wave_reduce_u(cnt);
    __shared__ double smd[4];
    __shared__ unsigned smu[4];
    if ((tid & 63) == 0) { smd[tid >> 6] = msum; smu[tid >> 6] = cnt; }
    __syncthreads();
    if (tid == 0) {
        pm[blockIdx.x] = smd[0] + smd[1] + smd[2] + smd[3];
        pc[blockIdx.x] = smu[0] + smu[1] + smu[2] + smu[3];
    }
}

// ---------- GEMM: C[m][n] = alpha * sum_k A[m][k]*B[n][k] + bias[n] ----------
// m97 structure + XOR-swizzled LDS sub-blocks (conflict-free ds_read_b128)
// + block-redundant alpha reduce in the epilogue.
__global__ __launch_bounds__(256) void ternary_gemm(
    const __bf16* __restrict__ A,    // M x K (x in bf16)
    const __bf16* __restrict__ B,    // N x K (ternary in bf16)
    const float*  __restrict__ bias, // N
    const double* __restrict__ scal, // [0] = mean|w| fallback
    const double* __restrict__ pm,   // 2048 masked partial sums
    const unsigned* __restrict__ pc, // 2048 masked partial counts
    float* __restrict__ C)           // M x N
{
    __shared__ __attribute__((aligned(128))) __bf16 As[128 * 32];
    __shared__ __attribute__((aligned(128))) __bf16 Bs[128 * 32];
    __shared__ double smd[4];
    __shared__ unsigned smu[4];

    const int tid  = threadIdx.x;
    const int wave = tid >> 6;
    const int lane = tid & 63;
    const int quad = lane >> 4;
    const int l16  = lane & 15;
    const int wr = wave >> 1;
    const int wc = wave & 1;

    const int br = blockIdx.y;
    const int bc = blockIdx.x;

    // staging: LDS position p = lane&3 within a 64B row holds global sub-block
    // q = p ^ ((srow>>1)&3)  (XOR swizzle -> conflict-free fragment reads)
    const int srow = lane >> 2;
    const int scol = ((lane & 3) ^ ((srow >> 1) & 3)) * 8;
    const int c0 = wave * 2;

    const __bf16* gA0 = A + (size_t)(br * 128 + c0 * 16 + srow) * K_DIM + scol;
    const __bf16* gA1 = gA0 + 16 * K_DIM;
    const __bf16* gB0 = B + (size_t)(bc * 128 + c0 * 16 + srow) * K_DIM + scol;
    const __bf16* gB1 = gB0 + 16 * K_DIM;
    __bf16* lA0 = &As[c0 * 512];
    __bf16* lA1 = &As[(c0 + 1) * 512];
    __bf16* lB0 = &Bs[c0 * 512];
    __bf16* lB1 = &Bs[(c0 + 1) * 512];

    floatx4 acc[4][4] = {};

    // fragment read: sub-block for (quad, row l16) sits at position quad ^ ((l16>>1)&3)
    const int swz = (quad ^ ((l16 >> 1) & 3)) * 8;
    const int a_off = (wr * 64 + l16) * 32 + swz;
    const int b_off = (wc * 64 + l16) * 32 + swz;

    for (int k0 = 0; k0 < K_DIM; k0 += 32) {
        async_copy16(gA0, lA0);
        async_copy16(gA1, lA1);
        async_copy16(gB0, lB0);
        async_copy16(gB1, lB1);
        gA0 += 32; gA1 += 32; gB0 += 32; gB1 += 32;
        __syncthreads();

        bf16x8 af[4], bfr[4];
        #pragma unroll
        for (int i = 0; i < 4; ++i)
            af[i] = *(const bf16x8*)&As[a_off + i * 512];
        #pragma unroll
        for (int j = 0; j < 4; ++j)
            bfr[j] = *(const bf16x8*)&Bs[b_off + j * 512];

        #pragma unroll
        for (int i = 0; i < 4; ++i)
            #pragma unroll
            for (int j = 0; j < 4; ++j)
                acc[i][j] = __builtin_amdgcn_mfma_f32_16x16x32_bf16(
                    af[i], bfr[j], acc[i][j], 0, 0, 0);
        __syncthreads();
    }

    // block-redundant alpha reduce (deterministic, identical in every block)
    double s = 0.0; unsigned c = 0;
    #pragma unroll
    for (int i = 0; i < 8; ++i) { s += pm[tid + i * 256]; c += pc[tid + i * 256]; }
    s = wave_reduce_d(s);
    c = wave_reduce_u(c);
    if ((tid & 63) == 0) { smd[tid >> 6] = s; smu[tid >> 6] = c; }
    __syncthreads();
    const double ms = smd[0] + smd[1] + smd[2] + smd[3];
    const unsigned ct = smu[0] + smu[1] + smu[2] + smu[3];
    const float alpha = (float)(ct > 0 ? ms / (double)ct : scal[0]);

    float bv[4];
    #pragma unroll
    for (int j = 0; j < 4; ++j)
        bv[j] = bias[bc * 128 + wc * 64 + j * 16 + l16];

    // C/D layout (16x16x32): col = lane&15, row = quad*4 + reg
    #pragma unroll
    for (int i = 0; i < 4; ++i) {
        const int row0 = br * 128 + wr * 64 + i * 16 + quad * 4;
        #pragma unroll
        for (int j = 0; j < 4; ++j) {
            const int col = bc * 128 + wc * 64 + j * 16 + l16;
            #pragma unroll
            for (int r = 0; r < 4; ++r)
                C[(size_t)(row0 + r) * N_DIM + col] = acc[i][j][r] * alpha + bv[j];
        }
    }
}

extern "C" void kernel_launch(void* const* d_in, const int* in_sizes, int n_in,
                              void* d_out, int out_size, void* d_ws, size_t ws_size,
                              hipStream_t stream) {
    const float* x    = (const float*)d_in[0];  // (8192, 4096) fp32
    const float* w    = (const float*)d_in[1];  // (4096, 4096) fp32
    const float* bias = (const float*)d_in[2];  // (4096,) fp32
    float* out = (float*)d_out;                 // (8192, 4096) fp32

    char* ws = (char*)d_ws;
    double*   d_scal = (double*)ws;               // [0] = mean|w|
    double*   part   = (double*)(ws + 64);        // 2048 doubles
    double*   pm     = (double*)(ws + 16448);     // 2048 doubles
    unsigned* pc     = (unsigned*)(ws + 32832);   // 2048 uints
    __bf16*   xb     = (__bf16*)(ws + 65536);                                   // 64 MB
    __bf16*   tern   = (__bf16*)(ws + 65536 + (size_t)M_DIM * K_DIM * 2);       // 32 MB

    k_pre<<<10240, 256, 0, stream>>>((const float4*)w, part, (const float4*)x, (bf16x4*)xb);
    k_quant<<<2048, 256, 0, stream>>>((const float4*)w, (bf16x4*)tern, part, d_scal, pm, pc);

    dim3 grid(N_DIM / 128, M_DIM / 128);  // (32, 64)
    ternary_gemm<<<grid, 256, 0, stream>>>(xb, tern, bias, d_scal, pm, pc, out);
}

// Round 3
// 554.667 us; speedup vs baseline: 1.0431x; 1.0431x over previous
//
#include <hip/hip_runtime.h>

#define M_DIM 8192
#define N_DIM 4096
#define K_DIM 4096

typedef __attribute__((ext_vector_type(8))) __bf16 bf16x8;
typedef __attribute__((ext_vector_type(4))) __bf16 bf16x4;
typedef __attribute__((ext_vector_type(4))) float floatx4;

// ---------- async global->LDS, 16B per lane (wave-uniform LDS base) ----------
__device__ __forceinline__ void async_copy16(const void* g, void* l) {
    __builtin_amdgcn_global_load_lds(
        (const __attribute__((address_space(1))) void*)g,
        (__attribute__((address_space(3))) void*)l,
        16, 0, 0);
}

// ---------- deterministic reductions (fp64) ----------
__device__ __forceinline__ double wave_reduce_d(double v) {
    #pragma unroll
    for (int o = 32; o > 0; o >>= 1) v += __shfl_down(v, o, 64);
    return v;
}
__device__ __forceinline__ unsigned wave_reduce_u(unsigned v) {
    #pragma unroll
    for (int o = 32; o > 0; o >>= 1) v += __shfl_down(v, o, 64);
    return v;
}

// K1 (fused): blocks [0,2048) -> partial sums of |W|; blocks [2048,10240) -> x fp32->bf16
__global__ __launch_bounds__(256) void k_pre(const float4* __restrict__ w4,
                                             double* __restrict__ part,
                                             const float4* __restrict__ x4,
                                             bf16x4* __restrict__ xb) {
    const int tid = threadIdx.x;
    if (blockIdx.x < 2048) {
        int idx = blockIdx.x * 256 + tid;
        double s = 0.0;
        #pragma unroll
        for (int it = 0; it < 8; ++it) {
            float4 v = w4[idx + it * (2048 * 256)];
            s += (double)fabsf(v.x) + (double)fabsf(v.y) +
                 (double)fabsf(v.z) + (double)fabsf(v.w);
        }
        s = wave_reduce_d(s);
        __shared__ double sm[4];
        if ((tid & 63) == 0) sm[tid >> 6] = s;
        __syncthreads();
        if (tid == 0) part[blockIdx.x] = sm[0] + sm[1] + sm[2] + sm[3];
    } else {
        int idx = (blockIdx.x - 2048) * 256 + tid;
        #pragma unroll
        for (int it = 0; it < 4; ++it) {
            int i = idx + it * (8192 * 256);
            float4 v = x4[i];
            bf16x4 o;
            o[0] = (__bf16)v.x; o[1] = (__bf16)v.y;
            o[2] = (__bf16)v.z; o[3] = (__bf16)v.w;
            xb[i] = o;
        }
    }
}

// K2: block-redundant delta from part[2048]; quantize; masked partial sums.
// Per-element math BIT-IDENTICAL to the round-1 passing kernel (f64 delta/compare).
__global__ __launch_bounds__(256) void k_quant(const float4* __restrict__ w4,
                                               bf16x4* __restrict__ tern,
                                               const double* __restrict__ part,
                                               double* __restrict__ scal,
                                               double* __restrict__ pm,
                                               unsigned* __restrict__ pc) {
    const int tid = threadIdx.x;
    double s = 0.0;
    #pragma unroll
    for (int i = 0; i < 8; ++i) s += part[tid + i * 256];
    s = wave_reduce_d(s);
    __shared__ double sm[4];
    if ((tid & 63) == 0) sm[tid >> 6] = s;
    __syncthreads();
    const double mean = (sm[0] + sm[1] + sm[2] + sm[3]) * (1.0 / 16777216.0);
    const double delta = 0.7 * mean;
    if (blockIdx.x == 0 && tid == 0) scal[0] = mean;

    int idx = blockIdx.x * 256 + tid;
    double msum = 0.0;
    unsigned cnt = 0;
    #pragma unroll
    for (int it = 0; it < 8; ++it) {
        int i = idx + it * (2048 * 256);
        float4 v = w4[i];
        float e[4] = {v.x, v.y, v.z, v.w};
        bf16x4 o;
        #pragma unroll
        for (int c = 0; c < 4; ++c) {
            float wv = e[c];
            float t = ((double)wv > delta) ? 1.0f
                    : (((double)wv < -delta) ? -1.0f : 0.0f);
            if (t != 0.0f) { msum += (double)fabsf(wv); cnt++; }
            o[c] = (__bf16)t;
        }
        tern[i] = o;
    }
    msum = wave_reduce_d(msum);
    cnt  = wave_reduce_u(cnt);
    __shared__ double smd[4];
    __shared__ unsigned smu[4];
    if ((tid & 63) == 0) { smd[tid >> 6] = msum; smu[tid >> 6] = cnt; }
    __syncthreads();
    if (tid == 0) {
        pm[blockIdx.x] = smd[0] + smd[1] + smd[2] + smd[3];
        pc[blockIdx.x] = smu[0] + smu[1] + smu[2] + smu[3];
    }
}

// ---------- GEMM: C[m][n] = alpha * sum_k A[m][k]*B[n][k] + bias[n] ----------
// Block tile 256x128, 4 waves, PER-WAVE 128x64 (8x4 MFMA frags) -> 25% less
// LDS fragment traffic per FLOP than 64x64/wave. XOR-swizzled LDS (0 conflicts).
__global__ __launch_bounds__(256, 2) void ternary_gemm(
    const __bf16* __restrict__ A,    // M x K (x in bf16)
    const __bf16* __restrict__ B,    // N x K (ternary in bf16)
    const float*  __restrict__ bias, // N
    const double* __restrict__ scal, // [0] = mean|w| fallback
    const double* __restrict__ pm,   // 2048 masked partial sums
    const unsigned* __restrict__ pc, // 2048 masked partial counts
    float* __restrict__ C)           // M x N
{
    __shared__ __attribute__((aligned(128))) __bf16 As[256 * 32];  // 16 KB
    __shared__ __attribute__((aligned(128))) __bf16 Bs[128 * 32];  // 8 KB
    __shared__ double smd[4];
    __shared__ unsigned smu[4];

    const int tid  = threadIdx.x;
    const int wave = tid >> 6;
    const int lane = tid & 63;
    const int quad = lane >> 4;
    const int l16  = lane & 15;
    const int wr = wave >> 1;   // row half: 128 rows
    const int wc = wave & 1;    // col half: 64 cols

    const int br = blockIdx.y;  // M tile (256)
    const int bc = blockIdx.x;  // N tile (128)

    // staging: chunk = 16 rows x 32 cols (1 KB). A: 16 chunks, B: 8 chunks.
    // wave w: A chunks 4w..4w+3, B chunks 2w..2w+1.
    // XOR swizzle: LDS pos (lane&3) holds global sub-block (lane&3)^((row>>1)&3).
    const int srow = lane >> 2;
    const int scol = ((lane & 3) ^ ((srow >> 1) & 3)) * 8;

    const __bf16* gA[4];
    const __bf16* gB[2];
    __bf16* lA[4];
    __bf16* lB[2];
    #pragma unroll
    for (int t = 0; t < 4; ++t) {
        const int c = wave * 4 + t;
        gA[t] = A + (size_t)(br * 256 + c * 16 + srow) * K_DIM + scol;
        lA[t] = &As[c * 512];
    }
    #pragma unroll
    for (int t = 0; t < 2; ++t) {
        const int c = wave * 2 + t;
        gB[t] = B + (size_t)(bc * 128 + c * 16 + srow) * K_DIM + scol;
        lB[t] = &Bs[c * 512];
    }

    floatx4 acc[8][4] = {};

    // fragment read: sub-block for (quad, row l16) sits at position quad^((l16>>1)&3)
    const int swz = (quad ^ ((l16 >> 1) & 3)) * 8;
    const int a_off = (wr * 128 + l16) * 32 + swz;
    const int b_off = (wc * 64 + l16) * 32 + swz;

    for (int k0 = 0; k0 < K_DIM; k0 += 32) {
        #pragma unroll
        for (int t = 0; t < 4; ++t) { async_copy16(gA[t], lA[t]); gA[t] += 32; }
        #pragma unroll
        for (int t = 0; t < 2; ++t) { async_copy16(gB[t], lB[t]); gB[t] += 32; }
        __syncthreads();

        bf16x8 af[8], bfr[4];
        #pragma unroll
        for (int i = 0; i < 8; ++i)
            af[i] = *(const bf16x8*)&As[a_off + i * 512];
        #pragma unroll
        for (int j = 0; j < 4; ++j)
            bfr[j] = *(const bf16x8*)&Bs[b_off + j * 512];

        #pragma unroll
        for (int i = 0; i < 8; ++i)
            #pragma unroll
            for (int j = 0; j < 4; ++j)
                acc[i][j] = __builtin_amdgcn_mfma_f32_16x16x32_bf16(
                    af[i], bfr[j], acc[i][j], 0, 0, 0);
        __syncthreads();
    }

    // block-redundant alpha reduce (deterministic, identical in every block)
    double s = 0.0; unsigned c = 0;
    #pragma unroll
    for (int i = 0; i < 8; ++i) { s += pm[tid + i * 256]; c += pc[tid + i * 256]; }
    s = wave_reduce_d(s);
    c = wave_reduce_u(c);
    if ((tid & 63) == 0) { smd[tid >> 6] = s; smu[tid >> 6] = c; }
    __syncthreads();
    const double ms = smd[0] + smd[1] + smd[2] + smd[3];
    const unsigned ct = smu[0] + smu[1] + smu[2] + smu[3];
    const float alpha = (float)(ct > 0 ? ms / (double)ct : scal[0]);

    float bv[4];
    #pragma unroll
    for (int j = 0; j < 4; ++j)
        bv[j] = bias[bc * 128 + wc * 64 + j * 16 + l16];

    // C/D layout (16x16x32): col = lane&15, row = quad*4 + reg
    #pragma unroll
    for (int i = 0; i < 8; ++i) {
        const int row0 = br * 256 + wr * 128 + i * 16 + quad * 4;
        #pragma unroll
        for (int j = 0; j < 4; ++j) {
            const int col = bc * 128 + wc * 64 + j * 16 + l16;
            #pragma unroll
            for (int r = 0; r < 4; ++r)
                C[(size_t)(row0 + r) * N_DIM + col] = acc[i][j][r] * alpha + bv[j];
        }
    }
}

extern "C" void kernel_launch(void* const* d_in, const int* in_sizes, int n_in,
                              void* d_out, int out_size, void* d_ws, size_t ws_size,
                              hipStream_t stream) {
    const float* x    = (const float*)d_in[0];  // (8192, 4096) fp32
    const float* w    = (const float*)d_in[1];  // (4096, 4096) fp32
    const float* bias = (const float*)d_in[2];  // (4096,) fp32
    float* out = (float*)d_out;                 // (8192, 4096) fp32

    char* ws = (char*)d_ws;
    double*   d_scal = (double*)ws;               // [0] = mean|w|
    double*   part   = (double*)(ws + 64);        // 2048 doubles
    double*   pm     = (double*)(ws + 16448);     // 2048 doubles
    unsigned* pc     = (unsigned*)(ws + 32832);   // 2048 uints
    __bf16*   xb     = (__bf16*)(ws + 65536);                                   // 64 MB
    __bf16*   tern   = (__bf16*)(ws + 65536 + (size_t)M_DIM * K_DIM * 2);       // 32 MB

    k_pre<<<10240, 256, 0, stream>>>((const float4*)w, part, (const float4*)x, (bf16x4*)xb);
    k_quant<<<2048, 256, 0, stream>>>((const float4*)w, (bf16x4*)tern, part, d_scal, pm, pc);

    dim3 grid(N_DIM / 128, M_DIM / 256);  // (32, 32)
    ternary_gemm<<<grid, 256, 0, stream>>>(xb, tern, bias, d_scal, pm, pc, out);
}